// Round 3
// baseline (446.252 us; speedup 1.0000x reference)
//
#include <hip/hip_runtime.h>
#include <hip/hip_bf16.h>
#include <hip/hip_fp16.h>

// Problem constants (fixed by the reference setup)
#define N_NODES 50000
#define N_EDGES 800000
#define E_TOT   (N_EDGES + N_NODES)   // 850000 (self-loops appended)
#define E_PAD   850048                // plane stride for per-edge weights
#define IN_C    256
#define H1C     256                    // HEADS * HID_C = 4*64
#define HEADS   4
#define HID_C   64
#define OUT_C   128
#define N_GRAPHS 100
#define NEG_SLOPE 0.2f
#define EPS_F 1e-16f
#define SCAN_BLOCKS 196               // ceil(N_NODES / 256)

// prep_kernel block partition
#define PREP_CAST_BLOCKS   12500      // 3,200,000 uint2 / 256
#define PREP_W1_BLOCKS     256        // 65536 / 256
#define PREP_W2_BLOCKS     128        // 32768 / 256
#define PREP_HIST_BLOCKS   3321       // ceil(850000/256)
#define PREP_BOUNDS_BLOCKS 196
#define PREP_DOUT_BLOCKS   50         // 12800 floats / 256
#define PREP_TOTAL (PREP_CAST_BLOCKS + PREP_W1_BLOCKS + PREP_W2_BLOCKS + PREP_HIST_BLOCKS + PREP_BOUNDS_BLOCKS + PREP_DOUT_BLOCKS)

typedef _Float16 half8_t __attribute__((ext_vector_type(8)));
typedef float f32x4 __attribute__((ext_vector_type(4)));

// ---------------------------------------------------------------------------
// Fused prep: cast_x + W1 transpose + W2 transpose + hist + bounds + d_out=0.
// ---------------------------------------------------------------------------
__global__ __launch_bounds__(256) void prep_kernel(const float* __restrict__ x,
                                                   _Float16* __restrict__ xh,
                                                   const float* __restrict__ W1,
                                                   _Float16* __restrict__ W1t,
                                                   const float* __restrict__ W2,
                                                   _Float16* __restrict__ W2t,
                                                   const int* __restrict__ ei,
                                                   int* __restrict__ hist,
                                                   const int* __restrict__ batch,
                                                   int* __restrict__ gstart,
                                                   float* __restrict__ d_out) {
    int b = blockIdx.x;
    int tid = threadIdx.x;
    if (b < PREP_CAST_BLOCKS) {
        int idx = b * 256 + tid;                      // < 3,200,000 exactly
        float4 v = reinterpret_cast<const float4*>(x)[idx];
        union { _Float16 h[4]; uint2 u; } p;
        p.h[0] = (_Float16)v.x; p.h[1] = (_Float16)v.y;
        p.h[2] = (_Float16)v.z; p.h[3] = (_Float16)v.w;
        reinterpret_cast<uint2*>(xh)[idx] = p.u;
        return;
    }
    b -= PREP_CAST_BLOCKS;
    if (b < PREP_W1_BLOCKS) {
        int idx = b * 256 + tid;                      // < 65536 exactly
        int n = idx >> 8, k = idx & 255;
        W1t[idx] = (_Float16)W1[k * 256 + n];
        return;
    }
    b -= PREP_W1_BLOCKS;
    if (b < PREP_W2_BLOCKS) {
        int idx = b * 256 + tid;                      // < 32768 exactly
        int n = idx >> 8, k = idx & 255;
        W2t[idx] = (_Float16)W2[k * 128 + n];
        return;
    }
    b -= PREP_W2_BLOCKS;
    if (b < PREP_HIST_BLOCKS) {
        int idx = b * 256 + tid;
        if (idx < N_EDGES) {
            int d = ei[N_EDGES + idx];
            if (d >= 0 && d < N_NODES) atomicAdd(&hist[d], 1);
        } else if (idx < E_TOT) {
            atomicAdd(&hist[idx - N_EDGES], 1);       // self loop
        }
        return;
    }
    b -= PREP_HIST_BLOCKS;
    if (b < PREP_BOUNDS_BLOCKS) {   // bounds: batch sorted; each gstart entry written exactly once
        int idx = b * 256 + tid;
        if (idx >= N_NODES) return;
        int g = batch[idx];
        if (g < 0) g = 0; if (g >= N_GRAPHS) g = N_GRAPHS - 1;
        if (idx == 0) {
            for (int j = 0; j <= g; ++j) gstart[j] = 0;
        } else {
            int gp = batch[idx - 1];
            if (gp < 0) gp = 0; if (gp >= N_GRAPHS) gp = N_GRAPHS - 1;
            for (int j = gp + 1; j <= g; ++j) gstart[j] = idx;
        }
        if (idx == N_NODES - 1) {
            for (int j = g + 1; j <= N_GRAPHS; ++j) gstart[j] = N_NODES;
        }
        return;
    }
    b -= PREP_BOUNDS_BLOCKS;
    {   // zero d_out (pool accumulates atomically much later in the stream)
        int idx = b * 256 + tid;
        if (idx < N_GRAPHS * 128) d_out[idx] = 0.f;
    }
}

// ---------------------------------------------------------------------------
// CSR scan (phase2 folded into phase3) + scatter
// ---------------------------------------------------------------------------
__global__ __launch_bounds__(256) void scan_phase1(const int* __restrict__ hist,
                                                   int* __restrict__ blockSums) {
    __shared__ int lds[256];
    int idx = blockIdx.x * 256 + threadIdx.x;
    int v = (idx < N_NODES) ? hist[idx] : 0;
    lds[threadIdx.x] = v;
    __syncthreads();
#pragma unroll
    for (int off = 128; off > 0; off >>= 1) {
        if (threadIdx.x < off) lds[threadIdx.x] += lds[threadIdx.x + off];
        __syncthreads();
    }
    if (threadIdx.x == 0) blockSums[blockIdx.x] = lds[0];
}

__global__ __launch_bounds__(256) void scan_phase3(const int* __restrict__ hist,
                                                   const int* __restrict__ blockSums,
                                                   int* __restrict__ row_ptr,
                                                   int* __restrict__ row_fill) {
    __shared__ int lds[256];
    __shared__ int s_off;
    int b = blockIdx.x;
    int t = threadIdx.x;
    // wave 0: exclusive block offset = sum(blockSums[0..b-1])
    if (t < 64) {
        int acc = 0;
        for (int i = t; i < b; i += 64) acc += blockSums[i];
#pragma unroll
        for (int off = 32; off > 0; off >>= 1) acc += __shfl_down(acc, off);
        if (t == 0) s_off = acc;
    }
    int idx = b * 256 + t;
    int v = (idx < N_NODES) ? hist[idx] : 0;
    lds[t] = v;
    __syncthreads();
#pragma unroll
    for (int off = 1; off < 256; off <<= 1) {
        int u = (t >= off) ? lds[t - off] : 0;
        __syncthreads();
        lds[t] += u;
        __syncthreads();
    }
    int excl = lds[t] - v + s_off;
    if (idx < N_NODES) {
        row_ptr[idx] = excl;
        row_fill[idx] = excl;
    }
    if (idx == N_NODES - 1) row_ptr[N_NODES] = excl + v;
}

__global__ __launch_bounds__(256) void scatter_kernel(const int* __restrict__ ei,
                                                      int* __restrict__ row_fill,
                                                      int* __restrict__ ssrc) {
    int idx = blockIdx.x * 256 + threadIdx.x;
    if (idx < N_EDGES) {
        int s = ei[idx];
        int d = ei[N_EDGES + idx];
        if (s < 0 || s >= N_NODES || d < 0 || d >= N_NODES) return;  // defensive
        int pos = atomicAdd(&row_fill[d], 1);
        if (pos >= 0 && pos < E_TOT) ssrc[pos] = s;
    } else if (idx < E_TOT) {
        int nd = idx - N_EDGES;
        int pos = atomicAdd(&row_fill[nd], 1);
        if (pos >= 0 && pos < E_TOT) ssrc[pos] = nd;
    }
}

// ---------------------------------------------------------------------------
// MFMA fp16 GEMM with folded attention dots (modes 1/2, verified rounds 10-12)
// ---------------------------------------------------------------------------
__global__ __launch_bounds__(256) void gemm_mfma_kernel(const _Float16* __restrict__ A,
                                                        const _Float16* __restrict__ Bt,
                                                        _Float16* __restrict__ C,
                                                        int mode,
                                                        const float* __restrict__ attS,
                                                        const float* __restrict__ attD,
                                                        float* __restrict__ a_src_o,
                                                        float* __restrict__ a_dst_o,
                                                        int M, int N) {
    __shared__ _Float16 As[128][48];   // ldk=48 keeps 16B alignment everywhere
    __shared__ _Float16 Bs[128][48];
    __shared__ float lds_ps[128];
    __shared__ float lds_pd[128];
    const int tid = threadIdx.x;
    const int tileM = blockIdx.x * 128;
    const int tileN = blockIdx.y * 128;
    const int w = tid >> 6, lane = tid & 63;
    const int wm = (w >> 1) * 64, wn = (w & 1) * 64;
    const int quad = lane >> 4, mlane = lane & 15;
    const int srow = tid >> 2;           // 0..63 (rows srow and srow+64)
    const int schunk = (tid & 3) * 8;    // f16 offset within 32-k slab

    f32x4 zero = {0.f, 0.f, 0.f, 0.f};
    f32x4 acc[4][4];
#pragma unroll
    for (int i = 0; i < 4; ++i)
#pragma unroll
        for (int j = 0; j < 4; ++j) acc[i][j] = zero;

    const uint4* Av = reinterpret_cast<const uint4*>(A);   // 8 f16 per uint4; 32/row
    const uint4* Bv = reinterpret_cast<const uint4*>(Bt);
    const int r0 = tileM + srow, r1 = r0 + 64;
    const bool ok0 = r0 < M, ok1 = r1 < M;
    const int bn0 = tileN + srow, bn1 = bn0 + 64;          // N mult of 128: no guard
    const uint4 z4 = make_uint4(0, 0, 0, 0);

    for (int k0 = 0; k0 < 256; k0 += 32) {
        const int kc = (k0 >> 3) + (tid & 3);
        uint4 a0 = ok0 ? Av[(size_t)r0 * 32 + kc] : z4;
        uint4 a1 = ok1 ? Av[(size_t)r1 * 32 + kc] : z4;
        uint4 b0 = Bv[(size_t)bn0 * 32 + kc];
        uint4 b1 = Bv[(size_t)bn1 * 32 + kc];
        __syncthreads();
        *reinterpret_cast<uint4*>(&As[srow][schunk]) = a0;
        *reinterpret_cast<uint4*>(&As[srow + 64][schunk]) = a1;
        *reinterpret_cast<uint4*>(&Bs[srow][schunk]) = b0;
        *reinterpret_cast<uint4*>(&Bs[srow + 64][schunk]) = b1;
        __syncthreads();
        half8_t af[4], bf[4];
#pragma unroll
        for (int mt = 0; mt < 4; ++mt)
            af[mt] = *reinterpret_cast<const half8_t*>(&As[wm + mt * 16 + mlane][quad * 8]);
#pragma unroll
        for (int nt = 0; nt < 4; ++nt)
            bf[nt] = *reinterpret_cast<const half8_t*>(&Bs[wn + nt * 16 + mlane][quad * 8]);
#pragma unroll
        for (int mt = 0; mt < 4; ++mt)
#pragma unroll
            for (int nt = 0; nt < 4; ++nt)
                acc[mt][nt] = __builtin_amdgcn_mfma_f32_16x16x32_f16(af[mt], bf[nt], acc[mt][nt], 0, 0, 0);
    }
#pragma unroll
    for (int mt = 0; mt < 4; ++mt) {
#pragma unroll
        for (int i = 0; i < 4; ++i) {
            int row = tileM + wm + mt * 16 + quad * 4 + i;
            if (row < M) {
                _Float16* cp = C + (size_t)row * N + tileN + wn;
#pragma unroll
                for (int nt = 0; nt < 4; ++nt)
                    cp[nt * 16 + mlane] = (_Float16)acc[mt][nt][i];
            }
        }
    }
    if (mode == 1) {
        int hd = (tileN + wn) >> 6;          // this wave's head (64 cols/head)
        float as[4], ad[4];
#pragma unroll
        for (int nt = 0; nt < 4; ++nt) {
            as[nt] = attS[hd * 64 + nt * 16 + mlane];
            ad[nt] = attD[hd * 64 + nt * 16 + mlane];
        }
#pragma unroll
        for (int mt = 0; mt < 4; ++mt) {
#pragma unroll
            for (int i = 0; i < 4; ++i) {
                float ps = acc[mt][0][i] * as[0] + acc[mt][1][i] * as[1]
                         + acc[mt][2][i] * as[2] + acc[mt][3][i] * as[3];
                float pd = acc[mt][0][i] * ad[0] + acc[mt][1][i] * ad[1]
                         + acc[mt][2][i] * ad[2] + acc[mt][3][i] * ad[3];
#pragma unroll
                for (int off = 1; off < 16; off <<= 1) {
                    ps += __shfl_xor(ps, off);
                    pd += __shfl_xor(pd, off);
                }
                if (mlane == 0) {
                    int row = tileM + wm + mt * 16 + quad * 4 + i;
                    if (row < M) {
                        a_src_o[row * 4 + hd] = ps;
                        a_dst_o[row * 4 + hd] = pd;
                    }
                }
            }
        }
    } else if (mode == 2) {
        // single-head: wave covers cols wn..wn+63 of 128 -> partial dots
        float as[4], ad[4];
#pragma unroll
        for (int nt = 0; nt < 4; ++nt) {
            as[nt] = attS[wn + nt * 16 + mlane];
            ad[nt] = attD[wn + nt * 16 + mlane];
        }
        float psa[4][4], pda[4][4];
#pragma unroll
        for (int mt = 0; mt < 4; ++mt) {
#pragma unroll
            for (int i = 0; i < 4; ++i) {
                float ps = acc[mt][0][i] * as[0] + acc[mt][1][i] * as[1]
                         + acc[mt][2][i] * as[2] + acc[mt][3][i] * as[3];
                float pd = acc[mt][0][i] * ad[0] + acc[mt][1][i] * ad[1]
                         + acc[mt][2][i] * ad[2] + acc[mt][3][i] * ad[3];
#pragma unroll
                for (int off = 1; off < 16; off <<= 1) {
                    ps += __shfl_xor(ps, off);
                    pd += __shfl_xor(pd, off);
                }
                psa[mt][i] = ps; pda[mt][i] = pd;
            }
        }
        __syncthreads();
        if (wn == 0 && mlane == 0) {
#pragma unroll
            for (int mt = 0; mt < 4; ++mt)
#pragma unroll
                for (int i = 0; i < 4; ++i) {
                    int lr = wm + mt * 16 + quad * 4 + i;
                    lds_ps[lr] = psa[mt][i];
                    lds_pd[lr] = pda[mt][i];
                }
        }
        __syncthreads();
        if (wn == 64 && mlane == 0) {
#pragma unroll
            for (int mt = 0; mt < 4; ++mt)
#pragma unroll
                for (int i = 0; i < 4; ++i) {
                    int lr = wm + mt * 16 + quad * 4 + i;
                    int row = tileM + lr;
                    if (row < M) {
                        a_src_o[row] = psa[mt][i] + lds_ps[lr];
                        a_dst_o[row] = pda[mt][i] + lds_pd[lr];
                    }
                }
        }
    }
}

__device__ __forceinline__ float lrelu(float x) { return x > 0.f ? x : NEG_SLOPE * x; }

// ---------------------------------------------------------------------------
// Phase A: per-edge softmax weights + per-node denominators.
// Gathers are 4-16B from a_src (<=800KB, L2-resident). 1 wave = 1 node,
// lanes parallel over edges. Weights stored in per-head planes so the
// channel-sliced phase B reads them as a sequential stream.
// ---------------------------------------------------------------------------
template<int NH>
__global__ __launch_bounds__(256) void edgew_kernel(const int* __restrict__ row_ptr,
                                                    const int* __restrict__ ssrc,
                                                    const float* __restrict__ a_src,
                                                    const float* __restrict__ a_dst,
                                                    float* __restrict__ wpl,   // NH planes, stride E_PAD
                                                    float* __restrict__ spl) { // NH planes, stride 50016
    int node = blockIdx.x * 4 + (threadIdx.x >> 6);
    int lane = threadIdx.x & 63;
    int start = row_ptr[node], end = row_ptr[node + 1];
    float ad[NH], s[NH];
#pragma unroll
    for (int h = 0; h < NH; ++h) { ad[h] = a_dst[node * NH + h]; s[h] = 0.f; }
    for (int e0 = start; e0 < end; e0 += 64) {
        int e = e0 + lane;
        bool v = e < end;
        int ec = v ? e : end - 1;
        int si = ssrc[ec];
#pragma unroll
        for (int h = 0; h < NH; ++h) {
            float w = __expf(lrelu(a_src[si * NH + h] + ad[h]));
            if (v) { wpl[h * E_PAD + e] = w; s[h] += w; }
        }
    }
#pragma unroll
    for (int off = 32; off > 0; off >>= 1)
#pragma unroll
        for (int h = 0; h < NH; ++h) s[h] += __shfl_xor(s[h], off);
    if (lane == 0)
#pragma unroll
        for (int h = 0; h < NH; ++h) spl[h * 50016 + node] = s[h];
}

// ---------------------------------------------------------------------------
// Phase B: channel-sliced weighted gather-aggregate. One pass covers 64
// channels (128B slice of each row) so the gather working set is 6.4MB and
// largely L2-resident. 1 wave = 1 node; 8 lanes per edge-slot (8 edges per
// gather instruction, each lane 16B = 8 fp16 ch). w precomputed by phase A.
// fmaf(__half2float(h), w, acc) forms v_fma_mix_f32 (no separate cvt).
// ---------------------------------------------------------------------------
template<int ROW_U4, bool HALF_OUT>
__global__ __launch_bounds__(256) void edgeagg_kernel(const int* __restrict__ row_ptr,
                                                      const int* __restrict__ ssrc,
                                                      const uint4* __restrict__ hrows,
                                                      const float* __restrict__ wpl,
                                                      const float* __restrict__ spl,
                                                      const float* __restrict__ bias_sl,
                                                      uint4* __restrict__ out_u4,
                                                      float4* __restrict__ out_f4,
                                                      int slice_u4) {
    int node = blockIdx.x * 4 + (threadIdx.x >> 6);
    int lane = threadIdx.x & 63;
    int eg = lane >> 3, cs = lane & 7;
    int start = row_ptr[node], end = row_ptr[node + 1], em1 = end - 1;
    float acc[8];
#pragma unroll
    for (int k = 0; k < 8; ++k) acc[k] = 0.f;
    for (int e0 = start; e0 < end; e0 += 8) {
        int e = e0 + eg;
        int ec = e <= em1 ? e : em1;
        int si = ssrc[ec];
        float w = wpl[ec];
        w = (e < end) ? w : 0.f;
        uint4 q = hrows[(size_t)si * ROW_U4 + slice_u4 + cs];
        const __half* qh = reinterpret_cast<const __half*>(&q);
#pragma unroll
        for (int k = 0; k < 8; ++k)
            acc[k] = fmaf(__half2float(qh[k]), w, acc[k]);
    }
#pragma unroll
    for (int off = 8; off < 64; off <<= 1)
#pragma unroll
        for (int k = 0; k < 8; ++k) acc[k] += __shfl_xor(acc[k], off);
    float inv = 1.0f / (spl[node] + EPS_F);
    if (lane < 8) {
        if (HALF_OUT) {
            union { _Float16 h[8]; uint4 u; } st;
#pragma unroll
            for (int k = 0; k < 8; ++k)
                st.h[k] = (_Float16)fmaxf(acc[k] * inv + bias_sl[cs * 8 + k], 0.f);
            out_u4[(size_t)node * ROW_U4 + slice_u4 + cs] = st.u;
        } else {
            float4 o0, o1;
            o0.x = fmaxf(acc[0] * inv + bias_sl[cs * 8 + 0], 0.f);
            o0.y = fmaxf(acc[1] * inv + bias_sl[cs * 8 + 1], 0.f);
            o0.z = fmaxf(acc[2] * inv + bias_sl[cs * 8 + 2], 0.f);
            o0.w = fmaxf(acc[3] * inv + bias_sl[cs * 8 + 3], 0.f);
            o1.x = fmaxf(acc[4] * inv + bias_sl[cs * 8 + 4], 0.f);
            o1.y = fmaxf(acc[5] * inv + bias_sl[cs * 8 + 5], 0.f);
            o1.z = fmaxf(acc[6] * inv + bias_sl[cs * 8 + 6], 0.f);
            o1.w = fmaxf(acc[7] * inv + bias_sl[cs * 8 + 7], 0.f);
            float4* o4 = out_f4 + (size_t)node * 32 + slice_u4 * 2 + cs * 2;
            o4[0] = o0;
            o4[1] = o1;
        }
    }
}

// ---------------------------------------------------------------------------
// Pooling with folded mean division.
// ---------------------------------------------------------------------------
#define POOL_CHUNK 64
__global__ __launch_bounds__(128) void pool_kernel(const float* __restrict__ out2,
                                                   const int* __restrict__ batch,
                                                   const int* __restrict__ gstart,
                                                   float* __restrict__ d_out) {
    int c = threadIdx.x;                 // channel 0..127
    int node0 = blockIdx.x * POOL_CHUNK;
    int nodeEnd = node0 + POOL_CHUNK; if (nodeEnd > N_NODES) nodeEnd = N_NODES;
    if (node0 >= N_NODES) return;
    int gprev = batch[node0];
    float acc = 0.f;
    for (int node = node0; node < nodeEnd; ++node) {
        int g = batch[node];
        if (g != gprev) {
            if (gprev >= 0 && gprev < N_GRAPHS) {
                float cnt = (float)(gstart[gprev + 1] - gstart[gprev]);
                if (cnt < 1.f) cnt = 1.f;
                atomicAdd(&d_out[gprev * 128 + c], acc / cnt);
            }
            acc = 0.f;
            gprev = g;
        }
        acc += out2[(size_t)node * 128 + c];
    }
    if (gprev >= 0 && gprev < N_GRAPHS) {
        float cnt = (float)(gstart[gprev + 1] - gstart[gprev]);
        if (cnt < 1.f) cnt = 1.f;
        atomicAdd(&d_out[gprev * 128 + c], acc / cnt);
    }
}

// ---------------------------------------------------------------------------
extern "C" void kernel_launch(void* const* d_in, const int* in_sizes, int n_in,
                              void* d_out_v, int out_size, void* d_ws, size_t ws_size,
                              hipStream_t stream) {
    const float* x      = (const float*)d_in[0];
    const float* W1     = (const float*)d_in[1];
    const float* att_s1 = (const float*)d_in[2];
    const float* att_d1 = (const float*)d_in[3];
    const float* bias1  = (const float*)d_in[4];
    const float* W2     = (const float*)d_in[5];
    const float* att_s2 = (const float*)d_in[6];
    const float* att_d2 = (const float*)d_in[7];
    const float* bias2  = (const float*)d_in[8];
    const int*   ei     = (const int*)d_in[9];
    const int*   batch  = (const int*)d_in[10];
    float* d_out = (float*)d_out_v;

    // Workspace layout (float units):
    //  [0, 6.4M)        xh fp16 [N,256]   ... after GEMM1: w1 planes (3.4M) + s1 planes (0.2M)
    //                                     ... after GEMM2: h2h fp16 [N,128] in [0,3.2M),
    //                                         w2 plane at 3.4M + s2 at 4.25M
    //  [6.4M, 12.8M)    h1h fp16 [N,256]  ... later reused as out2 fp32 [N,128]
    //  [12.8M, 19.2M)   out1h fp16 [N,256]
    //  [19.2M, ...)     attention scalars + CSR ints + W transposes
    float* ws = (float*)d_ws;
    _Float16* xh    = (_Float16*)ws;
    _Float16* h1h   = (_Float16*)(ws + 6400000);
    _Float16* out1h = (_Float16*)(ws + 12800000);
    _Float16* h2h   = (_Float16*)ws;            // xh dead after GEMM1
    float*    out2  = ws + 6400000;             // h1h dead after edge1 phases
    float* w1pl   = ws;                         // 4 * E_PAD floats (xh dead after GEMM1)
    float* s1pl   = ws + 4 * E_PAD;             // 4 * 50016
    float* w2pl   = ws + 3400192;               // 850048 (beyond h2h's 3.2M floats)
    float* s2pl   = ws + 3400192 + E_PAD;       // 50016
    float* a_src1 = ws + 19200000;              // N*4
    float* a_dst1 = a_src1 + 200000;            // N*4
    float* a_src2 = a_dst1 + 200000;            // N
    float* a_dst2 = a_src2 + 50000;             // N
    int* hist     = (int*)(a_dst2 + 50000);     // N
    int* row_ptr  = hist + 50000;               // N+1 (padded to 50016)
    int* row_fill = row_ptr + 50016;            // N (padded to 50016)
    int* ssrc     = row_fill + 50016;           // E_TOT
    int* gstart   = ssrc + E_TOT;               // N_GRAPHS+1 (pad 128)
    int* blockSums    = gstart + 128;           // SCAN_BLOCKS
    int* blockOffsets = blockSums + SCAN_BLOCKS;     // (unused now; keeps layout)
    _Float16* W1t = (_Float16*)(blockOffsets + 256); // 65536 halfs [256][256]
    _Float16* W2t = W1t + 65536;                     // 32768 halfs [128][256]

    // Zero what must be zero (d_out zeroing folded into prep_kernel)
    hipMemsetAsync(hist, 0, N_NODES * sizeof(int), stream);

    // Fused prep: cast x, transpose W1/W2, histogram, graph bounds, d_out=0
    prep_kernel<<<PREP_TOTAL, 256, 0, stream>>>(x, xh, W1, W1t, W2, W2t,
                                                ei, hist, batch, gstart, d_out);

    // CSR scan (2 kernels) + scatter
    scan_phase1<<<SCAN_BLOCKS, 256, 0, stream>>>(hist, blockSums);
    scan_phase3<<<SCAN_BLOCKS, 256, 0, stream>>>(hist, blockSums, row_ptr, row_fill);
    scatter_kernel<<<(E_TOT + 255) / 256, 256, 0, stream>>>(ei, row_fill, ssrc);

    // Layer 1: h1 = x @ W1 (MFMA fp16, att1 folded into epilogue, mode 1)
    {
        dim3 g((N_NODES + 127) / 128, H1C / 128);
        gemm_mfma_kernel<<<g, 256, 0, stream>>>(xh, W1t, h1h, 1,
                                                att_s1, att_d1, a_src1, a_dst1,
                                                N_NODES, H1C);
    }
    // Layer 1 aggregation: phase A (weights) + 4 channel-sliced phase-B passes
    edgew_kernel<4><<<N_NODES / 4, 256, 0, stream>>>(row_ptr, ssrc, a_src1, a_dst1,
                                                     w1pl, s1pl);
    for (int p = 0; p < 4; ++p) {
        edgeagg_kernel<32, true><<<N_NODES / 4, 256, 0, stream>>>(
            row_ptr, ssrc, (const uint4*)h1h, w1pl + p * E_PAD, s1pl + p * 50016,
            bias1 + p * 64, (uint4*)out1h, nullptr, p * 8);
    }

    // Layer 2: h2 = out1 @ W2 (MFMA fp16, att2 folded via LDS combine, mode 2)
    {
        dim3 g((N_NODES + 127) / 128, OUT_C / 128);
        gemm_mfma_kernel<<<g, 256, 0, stream>>>(out1h, W2t, h2h, 2,
                                                att_s2, att_d2, a_src2, a_dst2,
                                                N_NODES, OUT_C);
    }
    // Layer 2 aggregation: phase A + 2 channel-sliced phase-B passes
    edgew_kernel<1><<<N_NODES / 4, 256, 0, stream>>>(row_ptr, ssrc, a_src2, a_dst2,
                                                     w2pl, s2pl);
    for (int p = 0; p < 2; ++p) {
        edgeagg_kernel<16, false><<<N_NODES / 4, 256, 0, stream>>>(
            row_ptr, ssrc, (const uint4*)h2h, w2pl, s2pl,
            bias2 + p * 64, nullptr, (float4*)out2, p * 8);
    }

    // Pooling (mean division folded into the atomic flush)
    pool_kernel<<<(N_NODES + POOL_CHUNK - 1) / POOL_CHUNK, 128, 0, stream>>>(out2, batch, gstart, d_out);
}

// Round 4
// 345.629 us; speedup vs baseline: 1.2911x; 1.2911x over previous
//
#include <hip/hip_runtime.h>
#include <hip/hip_bf16.h>
#include <hip/hip_fp16.h>

// Problem constants (fixed by the reference setup)
#define N_NODES 50000
#define N_EDGES 800000
#define E_TOT   (N_EDGES + N_NODES)   // 850000 (self-loops appended)
#define IN_C    256
#define H1C     256                    // HEADS * HID_C = 4*64
#define HEADS   4
#define HID_C   64
#define OUT_C   128
#define N_GRAPHS 100
#define NEG_SLOPE 0.2f
#define EPS_F 1e-16f
#define SCAN_BLOCKS 196               // ceil(N_NODES / 256)

// Bucket sort (replaces atomic scatter; kills 64B partial-line write-through)
#define NBUCKET 391                   // ceil(50000 / 128), bucket = dst >> 7
#define SORT_BLOCKS 104
#define EDGES_PER_SB 8192             // 104*8192 = 851968 >= E_TOT
#define BH_STRIDE 392                 // padded bucket-hist row
#define STAGE_CAP 3072                // LDS staging (span avg ~2176, +19 sigma)

// prep_kernel block partition
#define PREP_CAST_BLOCKS   12500      // 3,200,000 uint2 / 256
#define PREP_W1_BLOCKS     256        // 65536 / 256
#define PREP_W2_BLOCKS     128        // 32768 / 256
#define PREP_HIST_BLOCKS   3321       // ceil(850000/256)
#define PREP_BOUNDS_BLOCKS 196
#define PREP_DOUT_BLOCKS   50         // 12800 floats / 256
#define PREP_TOTAL (PREP_CAST_BLOCKS + PREP_W1_BLOCKS + PREP_W2_BLOCKS + PREP_HIST_BLOCKS + PREP_BOUNDS_BLOCKS + PREP_DOUT_BLOCKS)

typedef _Float16 half8_t __attribute__((ext_vector_type(8)));
typedef float f32x4 __attribute__((ext_vector_type(4)));

// ---------------------------------------------------------------------------
// Fused prep: cast_x + W1 transpose + W2 transpose + hist + bounds + d_out=0.
// ---------------------------------------------------------------------------
__global__ __launch_bounds__(256) void prep_kernel(const float* __restrict__ x,
                                                   _Float16* __restrict__ xh,
                                                   const float* __restrict__ W1,
                                                   _Float16* __restrict__ W1t,
                                                   const float* __restrict__ W2,
                                                   _Float16* __restrict__ W2t,
                                                   const int* __restrict__ ei,
                                                   int* __restrict__ hist,
                                                   const int* __restrict__ batch,
                                                   int* __restrict__ gstart,
                                                   float* __restrict__ d_out) {
    int b = blockIdx.x;
    int tid = threadIdx.x;
    if (b < PREP_CAST_BLOCKS) {
        int idx = b * 256 + tid;                      // < 3,200,000 exactly
        float4 v = reinterpret_cast<const float4*>(x)[idx];
        union { _Float16 h[4]; uint2 u; } p;
        p.h[0] = (_Float16)v.x; p.h[1] = (_Float16)v.y;
        p.h[2] = (_Float16)v.z; p.h[3] = (_Float16)v.w;
        reinterpret_cast<uint2*>(xh)[idx] = p.u;
        return;
    }
    b -= PREP_CAST_BLOCKS;
    if (b < PREP_W1_BLOCKS) {
        int idx = b * 256 + tid;                      // < 65536 exactly
        int n = idx >> 8, k = idx & 255;
        W1t[idx] = (_Float16)W1[k * 256 + n];
        return;
    }
    b -= PREP_W1_BLOCKS;
    if (b < PREP_W2_BLOCKS) {
        int idx = b * 256 + tid;                      // < 32768 exactly
        int n = idx >> 8, k = idx & 255;
        W2t[idx] = (_Float16)W2[k * 128 + n];
        return;
    }
    b -= PREP_W2_BLOCKS;
    if (b < PREP_HIST_BLOCKS) {
        int idx = b * 256 + tid;
        if (idx < N_EDGES) {
            int d = ei[N_EDGES + idx];
            if (d >= 0 && d < N_NODES) atomicAdd(&hist[d], 1);
        } else if (idx < E_TOT) {
            atomicAdd(&hist[idx - N_EDGES], 1);       // self loop
        }
        return;
    }
    b -= PREP_HIST_BLOCKS;
    if (b < PREP_BOUNDS_BLOCKS) {   // bounds: batch sorted; each gstart entry written exactly once
        int idx = b * 256 + tid;
        if (idx >= N_NODES) return;
        int g = batch[idx];
        if (g < 0) g = 0; if (g >= N_GRAPHS) g = N_GRAPHS - 1;
        if (idx == 0) {
            for (int j = 0; j <= g; ++j) gstart[j] = 0;
        } else {
            int gp = batch[idx - 1];
            if (gp < 0) gp = 0; if (gp >= N_GRAPHS) gp = N_GRAPHS - 1;
            for (int j = gp + 1; j <= g; ++j) gstart[j] = idx;
        }
        if (idx == N_NODES - 1) {
            for (int j = g + 1; j <= N_GRAPHS; ++j) gstart[j] = N_NODES;
        }
        return;
    }
    b -= PREP_BOUNDS_BLOCKS;
    {   // zero d_out (pool accumulates atomically much later in the stream)
        int idx = b * 256 + tid;
        if (idx < N_GRAPHS * 128) d_out[idx] = 0.f;
    }
}

// ---------------------------------------------------------------------------
// CSR scan (phase2 folded into phase3)
// ---------------------------------------------------------------------------
__global__ __launch_bounds__(256) void scan_phase1(const int* __restrict__ hist,
                                                   int* __restrict__ blockSums) {
    __shared__ int lds[256];
    int idx = blockIdx.x * 256 + threadIdx.x;
    int v = (idx < N_NODES) ? hist[idx] : 0;
    lds[threadIdx.x] = v;
    __syncthreads();
#pragma unroll
    for (int off = 128; off > 0; off >>= 1) {
        if (threadIdx.x < off) lds[threadIdx.x] += lds[threadIdx.x + off];
        __syncthreads();
    }
    if (threadIdx.x == 0) blockSums[blockIdx.x] = lds[0];
}

__global__ __launch_bounds__(256) void scan_phase3(const int* __restrict__ hist,
                                                   const int* __restrict__ blockSums,
                                                   int* __restrict__ row_ptr) {
    __shared__ int lds[256];
    __shared__ int s_off;
    int b = blockIdx.x;
    int t = threadIdx.x;
    // wave 0: exclusive block offset = sum(blockSums[0..b-1])
    if (t < 64) {
        int acc = 0;
        for (int i = t; i < b; i += 64) acc += blockSums[i];
#pragma unroll
        for (int off = 32; off > 0; off >>= 1) acc += __shfl_down(acc, off);
        if (t == 0) s_off = acc;
    }
    int idx = b * 256 + t;
    int v = (idx < N_NODES) ? hist[idx] : 0;
    lds[t] = v;
    __syncthreads();
#pragma unroll
    for (int off = 1; off < 256; off <<= 1) {
        int u = (t >= off) ? lds[t - off] : 0;
        __syncthreads();
        lds[t] += u;
        __syncthreads();
    }
    int excl = lds[t] - v + s_off;
    if (idx < N_NODES) row_ptr[idx] = excl;
    if (idx == N_NODES - 1) row_ptr[N_NODES] = excl + v;
}

// ---------------------------------------------------------------------------
// Bucket counting sort: dest-sorted ssrc with coalesced writes.
// S1: per-(block,bucket) histogram (LDS atomics, coalesced global write).
// S2: per-bucket exclusive prefix over blocks (bucket base = row_ptr[j*128]).
// S3: binned write of packed (src | dlow<<16) records, LDS cursors -> runs
//     of ~84B per (block,bucket): lines single-owner, L2 write-back once.
// S4: per-bucket LDS scatter + coalesced flush to ssrc.
// ---------------------------------------------------------------------------
__global__ __launch_bounds__(256) void bucket_hist(const int* __restrict__ ei,
                                                   int* __restrict__ bhist) {
    __shared__ int bh[NBUCKET];
    int tid = threadIdx.x;
    for (int t = tid; t < NBUCKET; t += 256) bh[t] = 0;
    __syncthreads();
    int base = blockIdx.x * EDGES_PER_SB;
#pragma unroll 4
    for (int k = 0; k < EDGES_PER_SB / 256; ++k) {
        int idx = base + k * 256 + tid;
        int d = -1;
        if (idx < N_EDGES) d = ei[N_EDGES + idx];
        else if (idx < E_TOT) d = idx - N_EDGES;
        if (d >= 0 && d < N_NODES) atomicAdd(&bh[d >> 7], 1);
    }
    __syncthreads();
    for (int t = tid; t < NBUCKET; t += 256)
        bhist[blockIdx.x * BH_STRIDE + t] = bh[t];
}

__global__ __launch_bounds__(64) void bucket_scan(int* __restrict__ bhist) {
    int j = blockIdx.x;              // bucket
    int lane = threadIdx.x;          // 0..63
    int carry = 0;
    for (int b0 = 0; b0 < SORT_BLOCKS; b0 += 64) {
        int b = b0 + lane;
        int v = (b < SORT_BLOCKS) ? bhist[b * BH_STRIDE + j] : 0;
        int inc = v;
#pragma unroll
        for (int off = 1; off < 64; off <<= 1) {
            int u = __shfl_up(inc, off);
            if (lane >= off) inc += u;
        }
        if (b < SORT_BLOCKS) bhist[b * BH_STRIDE + j] = inc - v + carry;
        carry += __shfl(inc, 63);
    }
}

__global__ __launch_bounds__(256) void bucket_bin(const int* __restrict__ ei,
                                                  const int* __restrict__ row_ptr,
                                                  const int* __restrict__ bhist,
                                                  int* __restrict__ ebuf) {
    __shared__ int cur[NBUCKET];
    int tid = threadIdx.x;
    for (int t = tid; t < NBUCKET; t += 256)
        cur[t] = row_ptr[t << 7] + bhist[blockIdx.x * BH_STRIDE + t];
    __syncthreads();
    int base = blockIdx.x * EDGES_PER_SB;
#pragma unroll 4
    for (int k = 0; k < EDGES_PER_SB / 256; ++k) {
        int idx = base + k * 256 + tid;
        int s = 0, d = -1;
        if (idx < N_EDGES) { s = ei[idx]; d = ei[N_EDGES + idx]; }
        else if (idx < E_TOT) { s = idx - N_EDGES; d = s; }
        if (d >= 0 && d < N_NODES) {
            int p = atomicAdd(&cur[d >> 7], 1);
            ebuf[p] = (s & 0xFFFF) | ((d & 127) << 16);
        }
    }
}

__global__ __launch_bounds__(256) void bucket_sort(const int* __restrict__ row_ptr,
                                                   const int* __restrict__ ebuf,
                                                   int* __restrict__ ssrc) {
    __shared__ int cur2[128];
    __shared__ int stage[STAGE_CAP];
    int j = blockIdx.x;
    int tid = threadIdx.x;
    int jn0 = j << 7;
    int nEnd = jn0 + 128; if (nEnd > N_NODES) nEnd = N_NODES;
    int lo = row_ptr[jn0];
    int hi = row_ptr[nEnd];
    int span = hi - lo;
    if (tid < nEnd - jn0) cur2[tid] = row_ptr[jn0 + tid] - lo;
    __syncthreads();
    if (span <= STAGE_CAP) {
        for (int t = lo + tid; t < hi; t += 256) {
            int v = ebuf[t];
            int p = atomicAdd(&cur2[v >> 16], 1);
            stage[p] = v & 0xFFFF;
        }
        __syncthreads();
        for (int t = tid; t < span; t += 256) ssrc[lo + t] = stage[t];
    } else {                         // overflow fallback (never for this input)
        for (int t = lo + tid; t < hi; t += 256) {
            int v = ebuf[t];
            int p = atomicAdd(&cur2[v >> 16], 1);
            ssrc[lo + p] = v & 0xFFFF;
        }
    }
}

// ---------------------------------------------------------------------------
// MFMA fp16 GEMM with folded attention dots (modes 1/2, verified rounds 10-12)
// ---------------------------------------------------------------------------
__global__ __launch_bounds__(256) void gemm_mfma_kernel(const _Float16* __restrict__ A,
                                                        const _Float16* __restrict__ Bt,
                                                        _Float16* __restrict__ C,
                                                        int mode,
                                                        const float* __restrict__ attS,
                                                        const float* __restrict__ attD,
                                                        float* __restrict__ a_src_o,
                                                        float* __restrict__ a_dst_o,
                                                        int M, int N) {
    __shared__ _Float16 As[128][48];   // ldk=48 keeps 16B alignment everywhere
    __shared__ _Float16 Bs[128][48];
    __shared__ float lds_ps[128];
    __shared__ float lds_pd[128];
    const int tid = threadIdx.x;
    const int tileM = blockIdx.x * 128;
    const int tileN = blockIdx.y * 128;
    const int w = tid >> 6, lane = tid & 63;
    const int wm = (w >> 1) * 64, wn = (w & 1) * 64;
    const int quad = lane >> 4, mlane = lane & 15;
    const int srow = tid >> 2;           // 0..63 (rows srow and srow+64)
    const int schunk = (tid & 3) * 8;    // f16 offset within 32-k slab

    f32x4 zero = {0.f, 0.f, 0.f, 0.f};
    f32x4 acc[4][4];
#pragma unroll
    for (int i = 0; i < 4; ++i)
#pragma unroll
        for (int j = 0; j < 4; ++j) acc[i][j] = zero;

    const uint4* Av = reinterpret_cast<const uint4*>(A);   // 8 f16 per uint4; 32/row
    const uint4* Bv = reinterpret_cast<const uint4*>(Bt);
    const int r0 = tileM + srow, r1 = r0 + 64;
    const bool ok0 = r0 < M, ok1 = r1 < M;
    const int bn0 = tileN + srow, bn1 = bn0 + 64;          // N mult of 128: no guard
    const uint4 z4 = make_uint4(0, 0, 0, 0);

    for (int k0 = 0; k0 < 256; k0 += 32) {
        const int kc = (k0 >> 3) + (tid & 3);
        uint4 a0 = ok0 ? Av[(size_t)r0 * 32 + kc] : z4;
        uint4 a1 = ok1 ? Av[(size_t)r1 * 32 + kc] : z4;
        uint4 b0 = Bv[(size_t)bn0 * 32 + kc];
        uint4 b1 = Bv[(size_t)bn1 * 32 + kc];
        __syncthreads();
        *reinterpret_cast<uint4*>(&As[srow][schunk]) = a0;
        *reinterpret_cast<uint4*>(&As[srow + 64][schunk]) = a1;
        *reinterpret_cast<uint4*>(&Bs[srow][schunk]) = b0;
        *reinterpret_cast<uint4*>(&Bs[srow + 64][schunk]) = b1;
        __syncthreads();
        half8_t af[4], bf[4];
#pragma unroll
        for (int mt = 0; mt < 4; ++mt)
            af[mt] = *reinterpret_cast<const half8_t*>(&As[wm + mt * 16 + mlane][quad * 8]);
#pragma unroll
        for (int nt = 0; nt < 4; ++nt)
            bf[nt] = *reinterpret_cast<const half8_t*>(&Bs[wn + nt * 16 + mlane][quad * 8]);
#pragma unroll
        for (int mt = 0; mt < 4; ++mt)
#pragma unroll
            for (int nt = 0; nt < 4; ++nt)
                acc[mt][nt] = __builtin_amdgcn_mfma_f32_16x16x32_f16(af[mt], bf[nt], acc[mt][nt], 0, 0, 0);
    }
#pragma unroll
    for (int mt = 0; mt < 4; ++mt) {
#pragma unroll
        for (int i = 0; i < 4; ++i) {
            int row = tileM + wm + mt * 16 + quad * 4 + i;
            if (row < M) {
                _Float16* cp = C + (size_t)row * N + tileN + wn;
#pragma unroll
                for (int nt = 0; nt < 4; ++nt)
                    cp[nt * 16 + mlane] = (_Float16)acc[mt][nt][i];
            }
        }
    }
    if (mode == 1) {
        int hd = (tileN + wn) >> 6;          // this wave's head (64 cols/head)
        float as[4], ad[4];
#pragma unroll
        for (int nt = 0; nt < 4; ++nt) {
            as[nt] = attS[hd * 64 + nt * 16 + mlane];
            ad[nt] = attD[hd * 64 + nt * 16 + mlane];
        }
#pragma unroll
        for (int mt = 0; mt < 4; ++mt) {
#pragma unroll
            for (int i = 0; i < 4; ++i) {
                float ps = acc[mt][0][i] * as[0] + acc[mt][1][i] * as[1]
                         + acc[mt][2][i] * as[2] + acc[mt][3][i] * as[3];
                float pd = acc[mt][0][i] * ad[0] + acc[mt][1][i] * ad[1]
                         + acc[mt][2][i] * ad[2] + acc[mt][3][i] * ad[3];
#pragma unroll
                for (int off = 1; off < 16; off <<= 1) {
                    ps += __shfl_xor(ps, off);
                    pd += __shfl_xor(pd, off);
                }
                if (mlane == 0) {
                    int row = tileM + wm + mt * 16 + quad * 4 + i;
                    if (row < M) {
                        a_src_o[row * 4 + hd] = ps;
                        a_dst_o[row * 4 + hd] = pd;
                    }
                }
            }
        }
    } else if (mode == 2) {
        // single-head: wave covers cols wn..wn+63 of 128 -> partial dots
        float as[4], ad[4];
#pragma unroll
        for (int nt = 0; nt < 4; ++nt) {
            as[nt] = attS[wn + nt * 16 + mlane];
            ad[nt] = attD[wn + nt * 16 + mlane];
        }
        float psa[4][4], pda[4][4];
#pragma unroll
        for (int mt = 0; mt < 4; ++mt) {
#pragma unroll
            for (int i = 0; i < 4; ++i) {
                float ps = acc[mt][0][i] * as[0] + acc[mt][1][i] * as[1]
                         + acc[mt][2][i] * as[2] + acc[mt][3][i] * as[3];
                float pd = acc[mt][0][i] * ad[0] + acc[mt][1][i] * ad[1]
                         + acc[mt][2][i] * ad[2] + acc[mt][3][i] * ad[3];
#pragma unroll
                for (int off = 1; off < 16; off <<= 1) {
                    ps += __shfl_xor(ps, off);
                    pd += __shfl_xor(pd, off);
                }
                psa[mt][i] = ps; pda[mt][i] = pd;
            }
        }
        __syncthreads();
        if (wn == 0 && mlane == 0) {
#pragma unroll
            for (int mt = 0; mt < 4; ++mt)
#pragma unroll
                for (int i = 0; i < 4; ++i) {
                    int lr = wm + mt * 16 + quad * 4 + i;
                    lds_ps[lr] = psa[mt][i];
                    lds_pd[lr] = pda[mt][i];
                }
        }
        __syncthreads();
        if (wn == 64 && mlane == 0) {
#pragma unroll
            for (int mt = 0; mt < 4; ++mt)
#pragma unroll
                for (int i = 0; i < 4; ++i) {
                    int lr = wm + mt * 16 + quad * 4 + i;
                    int row = tileM + lr;
                    if (row < M) {
                        a_src_o[row] = psa[mt][i] + lds_ps[lr];
                        a_dst_o[row] = pda[mt][i] + lds_pd[lr];
                    }
                }
        }
    }
}

__device__ __forceinline__ float lrelu(float x) { return x > 0.f ? x : NEG_SLOPE * x; }

// ---------------------------------------------------------------------------
// Edge aggregation, layer 1 — round-2 form (verified 65us): 1 wave = 1 node,
// each load covers TWO edges (lanes 0-31 even / 32-63 odd; 16B uint4 per
// lane = 8 channels). Full predication; __shfl_xor(.,32) folds halves.
// ---------------------------------------------------------------------------
__global__ __launch_bounds__(256) void edge1_kernel(const int* __restrict__ row_ptr,
                                                    const int* __restrict__ ssrc,
                                                    const __half* __restrict__ h1h,
                                                    const float* __restrict__ a_src,
                                                    const float* __restrict__ a_dst,
                                                    const float* __restrict__ bias,
                                                    __half* __restrict__ out) {
    int node = blockIdx.x * 4 + (threadIdx.x >> 6);
    int lane = threadIdx.x & 63;
    int hf   = lane >> 5;              // 0: even edges, 1: odd edges
    int cl   = lane & 31;              // channel-lane: ch [cl*8, cl*8+8)
    int hd   = cl >> 3;                // head = ch/64
    int start = row_ptr[node], end = row_ptr[node + 1];
    int em1 = end - 1;                 // >= start (self-loop guarantees deg>=1)
    float adh = a_dst[node * 4 + hd];

    const uint4* h1v = reinterpret_cast<const uint4*>(h1h);   // 8 halfs/uint4; 32 per row
    float4 aA0 = make_float4(0.f,0.f,0.f,0.f), aA1 = make_float4(0.f,0.f,0.f,0.f);
    float4 aB0 = make_float4(0.f,0.f,0.f,0.f), aB1 = make_float4(0.f,0.f,0.f,0.f);
    float s = 0.f;
    for (int e = start; e < end; e += 4) {
        int e0 = e + hf;
        int e1 = e + 2 + hf;
        int i0 = ssrc[e0 <= em1 ? e0 : em1];
        int i1 = ssrc[e1 <= em1 ? e1 : em1];
        float r0 = a_src[i0 * 4 + hd];
        float r1 = a_src[i1 * 4 + hd];
        uint4 q0 = h1v[(size_t)i0 * 32 + cl];
        uint4 q1 = h1v[(size_t)i1 * 32 + cl];
        float w0 = (e0 < end) ? __expf(lrelu(r0 + adh)) : 0.f;
        float w1 = (e1 < end) ? __expf(lrelu(r1 + adh)) : 0.f;
        s += w0 + w1;
        float2 f;
        f = __half22float2(*reinterpret_cast<const __half2*>(&q0.x)); aA0.x += w0*f.x; aA0.y += w0*f.y;
        f = __half22float2(*reinterpret_cast<const __half2*>(&q0.y)); aA0.z += w0*f.x; aA0.w += w0*f.y;
        f = __half22float2(*reinterpret_cast<const __half2*>(&q0.z)); aA1.x += w0*f.x; aA1.y += w0*f.y;
        f = __half22float2(*reinterpret_cast<const __half2*>(&q0.w)); aA1.z += w0*f.x; aA1.w += w0*f.y;
        f = __half22float2(*reinterpret_cast<const __half2*>(&q1.x)); aB0.x += w1*f.x; aB0.y += w1*f.y;
        f = __half22float2(*reinterpret_cast<const __half2*>(&q1.y)); aB0.z += w1*f.x; aB0.w += w1*f.y;
        f = __half22float2(*reinterpret_cast<const __half2*>(&q1.z)); aB1.x += w1*f.x; aB1.y += w1*f.y;
        f = __half22float2(*reinterpret_cast<const __half2*>(&q1.w)); aB1.z += w1*f.x; aB1.w += w1*f.y;
    }
    float4 c0, c1;
    c0.x = aA0.x + aB0.x; c0.y = aA0.y + aB0.y; c0.z = aA0.z + aB0.z; c0.w = aA0.w + aB0.w;
    c1.x = aA1.x + aB1.x; c1.y = aA1.y + aB1.y; c1.z = aA1.z + aB1.z; c1.w = aA1.w + aB1.w;
    // fold even/odd halves (lane L and L+32 cover the same channels & head)
    c0.x += __shfl_xor(c0.x, 32); c0.y += __shfl_xor(c0.y, 32);
    c0.z += __shfl_xor(c0.z, 32); c0.w += __shfl_xor(c0.w, 32);
    c1.x += __shfl_xor(c1.x, 32); c1.y += __shfl_xor(c1.y, 32);
    c1.z += __shfl_xor(c1.z, 32); c1.w += __shfl_xor(c1.w, 32);
    s += __shfl_xor(s, 32);
    float inv = 1.0f / (s + EPS_F);
    if (lane < 32) {
        const float4* b4 = reinterpret_cast<const float4*>(bias);
        float4 b0 = b4[cl * 2], b1 = b4[cl * 2 + 1];
        union { _Float16 h[8]; uint4 u; } st;
        st.h[0] = (_Float16)fmaxf(c0.x * inv + b0.x, 0.f);
        st.h[1] = (_Float16)fmaxf(c0.y * inv + b0.y, 0.f);
        st.h[2] = (_Float16)fmaxf(c0.z * inv + b0.z, 0.f);
        st.h[3] = (_Float16)fmaxf(c0.w * inv + b0.w, 0.f);
        st.h[4] = (_Float16)fmaxf(c1.x * inv + b1.x, 0.f);
        st.h[5] = (_Float16)fmaxf(c1.y * inv + b1.y, 0.f);
        st.h[6] = (_Float16)fmaxf(c1.z * inv + b1.z, 0.f);
        st.h[7] = (_Float16)fmaxf(c1.w * inv + b1.w, 0.f);
        reinterpret_cast<uint4*>(out)[(size_t)node * 32 + cl] = st.u;
    }
}

// ---------------------------------------------------------------------------
// Edge aggregation, layer 2 — round-2 form: 2 nodes per wave, 16-lane groups
// cover the 128-ch row via one uint4 gather, two edges per iteration.
// ---------------------------------------------------------------------------
__global__ __launch_bounds__(256) void edge2_kernel(const int* __restrict__ row_ptr,
                                                    const int* __restrict__ ssrc,
                                                    const __half* __restrict__ h2h,
                                                    const float* __restrict__ a_src,
                                                    const float* __restrict__ a_dst,
                                                    const float* __restrict__ bias,
                                                    float* __restrict__ out) {
    int lane = threadIdx.x & 63;
    int node = blockIdx.x * 8 + ((threadIdx.x >> 6) << 1) + (lane >> 5);
    int sub  = (lane >> 4) & 1;        // edge sub-slot within the 32-lane node group
    int cl   = lane & 15;              // channel-lane: ch [cl*8, cl*8+8)
    int start = row_ptr[node], end = row_ptr[node + 1];
    int em1 = end - 1;
    float ad = a_dst[node];

    const uint4* h2v = reinterpret_cast<const uint4*>(h2h);   // 8 halfs/uint4; 16 per row
    float4 aA0 = make_float4(0.f,0.f,0.f,0.f), aA1 = make_float4(0.f,0.f,0.f,0.f);
    float4 aB0 = make_float4(0.f,0.f,0.f,0.f), aB1 = make_float4(0.f,0.f,0.f,0.f);
    float s = 0.f;
    for (int e = start; e < end; e += 4) {
        int e0 = e + sub;
        int e1 = e + 2 + sub;
        int i0 = ssrc[e0 <= em1 ? e0 : em1];
        int i1 = ssrc[e1 <= em1 ? e1 : em1];
        float r0 = a_src[i0];
        float r1 = a_src[i1];
        uint4 q0 = h2v[(size_t)i0 * 16 + cl];
        uint4 q1 = h2v[(size_t)i1 * 16 + cl];
        float w0 = (e0 < end) ? __expf(lrelu(r0 + ad)) : 0.f;
        float w1 = (e1 < end) ? __expf(lrelu(r1 + ad)) : 0.f;
        s += w0 + w1;
        float2 f;
        f = __half22float2(*reinterpret_cast<const __half2*>(&q0.x)); aA0.x += w0*f.x; aA0.y += w0*f.y;
        f = __half22float2(*reinterpret_cast<const __half2*>(&q0.y)); aA0.z += w0*f.x; aA0.w += w0*f.y;
        f = __half22float2(*reinterpret_cast<const __half2*>(&q0.z)); aA1.x += w0*f.x; aA1.y += w0*f.y;
        f = __half22float2(*reinterpret_cast<const __half2*>(&q0.w)); aA1.z += w0*f.x; aA1.w += w0*f.y;
        f = __half22float2(*reinterpret_cast<const __half2*>(&q1.x)); aB0.x += w1*f.x; aB0.y += w1*f.y;
        f = __half22float2(*reinterpret_cast<const __half2*>(&q1.y)); aB0.z += w1*f.x; aB0.w += w1*f.y;
        f = __half22float2(*reinterpret_cast<const __half2*>(&q1.z)); aB1.x += w1*f.x; aB1.y += w1*f.y;
        f = __half22float2(*reinterpret_cast<const __half2*>(&q1.w)); aB1.z += w1*f.x; aB1.w += w1*f.y;
    }
    float4 c0, c1;
    c0.x = aA0.x + aB0.x; c0.y = aA0.y + aB0.y; c0.z = aA0.z + aB0.z; c0.w = aA0.w + aB0.w;
    c1.x = aA1.x + aB1.x; c1.y = aA1.y + aB1.y; c1.z = aA1.z + aB1.z; c1.w = aA1.w + aB1.w;
    // fold the two 16-lane edge groups within this node's 32-lane half
    c0.x += __shfl_xor(c0.x, 16); c0.y += __shfl_xor(c0.y, 16);
    c0.z += __shfl_xor(c0.z, 16); c0.w += __shfl_xor(c0.w, 16);
    c1.x += __shfl_xor(c1.x, 16); c1.y += __shfl_xor(c1.y, 16);
    c1.z += __shfl_xor(c1.z, 16); c1.w += __shfl_xor(c1.w, 16);
    s += __shfl_xor(s, 16);
    float inv = 1.0f / (s + EPS_F);
    if (sub == 0) {                     // 16 lanes per node write the 128-ch row
        const float4* b4 = reinterpret_cast<const float4*>(bias);
        float4 b0 = b4[cl * 2], b1 = b4[cl * 2 + 1];
        float4 o0, o1;
        o0.x = fmaxf(c0.x * inv + b0.x, 0.f);
        o0.y = fmaxf(c0.y * inv + b0.y, 0.f);
        o0.z = fmaxf(c0.z * inv + b0.z, 0.f);
        o0.w = fmaxf(c0.w * inv + b0.w, 0.f);
        o1.x = fmaxf(c1.x * inv + b1.x, 0.f);
        o1.y = fmaxf(c1.y * inv + b1.y, 0.f);
        o1.z = fmaxf(c1.z * inv + b1.z, 0.f);
        o1.w = fmaxf(c1.w * inv + b1.w, 0.f);
        float4* o4 = reinterpret_cast<float4*>(out) + (size_t)node * 32 + cl * 2;
        o4[0] = o0;
        o4[1] = o1;
    }
}

// ---------------------------------------------------------------------------
// Pooling with folded mean division.
// ---------------------------------------------------------------------------
#define POOL_CHUNK 64
__global__ __launch_bounds__(128) void pool_kernel(const float* __restrict__ out2,
                                                   const int* __restrict__ batch,
                                                   const int* __restrict__ gstart,
                                                   float* __restrict__ d_out) {
    int c = threadIdx.x;                 // channel 0..127
    int node0 = blockIdx.x * POOL_CHUNK;
    int nodeEnd = node0 + POOL_CHUNK; if (nodeEnd > N_NODES) nodeEnd = N_NODES;
    if (node0 >= N_NODES) return;
    int gprev = batch[node0];
    float acc = 0.f;
    for (int node = node0; node < nodeEnd; ++node) {
        int g = batch[node];
        if (g != gprev) {
            if (gprev >= 0 && gprev < N_GRAPHS) {
                float cnt = (float)(gstart[gprev + 1] - gstart[gprev]);
                if (cnt < 1.f) cnt = 1.f;
                atomicAdd(&d_out[gprev * 128 + c], acc / cnt);
            }
            acc = 0.f;
            gprev = g;
        }
        acc += out2[(size_t)node * 128 + c];
    }
    if (gprev >= 0 && gprev < N_GRAPHS) {
        float cnt = (float)(gstart[gprev + 1] - gstart[gprev]);
        if (cnt < 1.f) cnt = 1.f;
        atomicAdd(&d_out[gprev * 128 + c], acc / cnt);
    }
}

// ---------------------------------------------------------------------------
extern "C" void kernel_launch(void* const* d_in, const int* in_sizes, int n_in,
                              void* d_out_v, int out_size, void* d_ws, size_t ws_size,
                              hipStream_t stream) {
    const float* x      = (const float*)d_in[0];
    const float* W1     = (const float*)d_in[1];
    const float* att_s1 = (const float*)d_in[2];
    const float* att_d1 = (const float*)d_in[3];
    const float* bias1  = (const float*)d_in[4];
    const float* W2     = (const float*)d_in[5];
    const float* att_s2 = (const float*)d_in[6];
    const float* att_d2 = (const float*)d_in[7];
    const float* bias2  = (const float*)d_in[8];
    const int*   ei     = (const int*)d_in[9];
    const int*   batch  = (const int*)d_in[10];
    float* d_out = (float*)d_out_v;

    // Workspace layout (float units):
    //  [0, 6.4M)        xh fp16 [N,256]      ... later reused as h2h fp16 [N,128]
    //  [6.4M, 12.8M)    h1h fp16 [N,256]     ... later reused as out2 fp32 [N,128]
    //  [12.8M, 19.2M)   out1h fp16 [N,256]
    //  [19.2M, ...)     attention scalars + CSR ints + sort buffers + W transposes
    float* ws = (float*)d_ws;
    _Float16* xh    = (_Float16*)ws;
    _Float16* h1h   = (_Float16*)(ws + 6400000);
    _Float16* out1h = (_Float16*)(ws + 12800000);
    _Float16* h2h   = (_Float16*)ws;            // xh dead after GEMM1
    float*    out2  = ws + 6400000;             // h1h dead after edge1
    float* a_src1 = ws + 19200000;              // N*4
    float* a_dst1 = a_src1 + 200000;            // N*4
    float* a_src2 = a_dst1 + 200000;            // N
    float* a_dst2 = a_src2 + 50000;             // N
    int* hist     = (int*)(a_dst2 + 50000);     // N
    int* row_ptr  = hist + 50000;               // N+1 (padded to 50016)
    int* ssrc     = row_ptr + 50016;            // E_TOT
    int* ebuf     = ssrc + 850000;              // SORT_BLOCKS*EDGES_PER_SB pad
    int* bhist    = ebuf + 851968;              // SORT_BLOCKS * BH_STRIDE
    int* gstart   = bhist + (SORT_BLOCKS * BH_STRIDE); // N_GRAPHS+1 (pad 128)
    int* blockSums = gstart + 128;              // SCAN_BLOCKS (pad 256)
    _Float16* W1t = (_Float16*)(blockSums + 256); // 65536 halfs [256][256]
    _Float16* W2t = W1t + 65536;                  // 32768 halfs [128][256]

    // Zero what must be zero (d_out zeroing folded into prep_kernel)
    hipMemsetAsync(hist, 0, N_NODES * sizeof(int), stream);

    // Fused prep: cast x, transpose W1/W2, histogram, graph bounds, d_out=0
    prep_kernel<<<PREP_TOTAL, 256, 0, stream>>>(x, xh, W1, W1t, W2, W2t,
                                                ei, hist, batch, gstart, d_out);

    // CSR scan
    scan_phase1<<<SCAN_BLOCKS, 256, 0, stream>>>(hist, blockSums);
    scan_phase3<<<SCAN_BLOCKS, 256, 0, stream>>>(hist, blockSums, row_ptr);

    // Bucket counting sort (replaces the partial-line-write-through scatter)
    bucket_hist<<<SORT_BLOCKS, 256, 0, stream>>>(ei, bhist);
    bucket_scan<<<NBUCKET, 64, 0, stream>>>(bhist);
    bucket_bin<<<SORT_BLOCKS, 256, 0, stream>>>(ei, row_ptr, bhist, ebuf);
    bucket_sort<<<NBUCKET, 256, 0, stream>>>(row_ptr, ebuf, ssrc);

    // Layer 1: h1 = x @ W1 (MFMA fp16, att1 folded into epilogue, mode 1)
    {
        dim3 g((N_NODES + 127) / 128, H1C / 128);
        gemm_mfma_kernel<<<g, 256, 0, stream>>>(xh, W1t, h1h, 1,
                                                att_s1, att_d1, a_src1, a_dst1,
                                                N_NODES, H1C);
    }
    edge1_kernel<<<N_NODES / 4, 256, 0, stream>>>(row_ptr, ssrc, (const __half*)h1h,
                                                  a_src1, a_dst1, bias1, (__half*)out1h);

    // Layer 2: h2 = out1 @ W2 (MFMA fp16, att2 folded via LDS combine, mode 2)
    {
        dim3 g((N_NODES + 127) / 128, OUT_C / 128);
        gemm_mfma_kernel<<<g, 256, 0, stream>>>(out1h, W2t, h2h, 2,
                                                att_s2, att_d2, a_src2, a_dst2,
                                                N_NODES, OUT_C);
    }
    edge2_kernel<<<N_NODES / 8, 256, 0, stream>>>(row_ptr, ssrc, (const __half*)h2h,
                                                  a_src2, a_dst2, bias2, out2);

    // Pooling (mean division folded into the atomic flush)
    pool_kernel<<<(N_NODES + POOL_CHUNK - 1) / POOL_CHUNK, 128, 0, stream>>>(out2, batch, gstart, d_out);
}